// Round 9
// baseline (243.524 us; speedup 1.0000x reference)
//
#include <hip/hip_runtime.h>
#include <hip/hip_bf16.h>

// N=8192 rows, BD=64 code dim, CD=512 channel dim
#define NN 8192
#define BD 64
#define CDIM 512

typedef __attribute__((ext_vector_type(4))) float f32x4;
typedef __attribute__((ext_vector_type(16))) float f32x16;
typedef __attribute__((ext_vector_type(4))) unsigned int u32x4;
typedef __attribute__((ext_vector_type(8))) __bf16 bf16x8;

// 32x32x16 fragment-major layouts (elems = unsigned short), frag = 512 ushorts = 1 KB:
//  adjF frag(it32,kt16): it32=i/32 [0,256), kt16=k/16 [0,512): off=(it32*512+kt16)*512+lane*8
//    lane l holds adj[it32*32 + (l&31)][kt16*16 + (l>>5)*8 + e]      (A-operand)
//  fcF  frag(nt32,kt16): nt32=n/32 [0,16),  kt16=k/16 [0,512): off=(nt32*512+kt16)*512+lane*8
//    lane l holds fc2[kt16*16 + (l>>5)*8 + e][nt32*32 + (l&31)]     (B-operand)
//  (operand mapping by symmetry with verified 16x16x32: idx=l&(M-1), k=8*(l>>log2M)+e)
//  cbnF/WF stay 16x16x32 frags for the small fc GEMM.

static __device__ __forceinline__ unsigned short f2bf(float x) {
    unsigned int u = __float_as_uint(x);
    u += 0x7fffu + ((u >> 16) & 1u);   // RTNE
    return (unsigned short)(u >> 16);
}

static __device__ __forceinline__ f32x4 mfma16(u32x4 a, u32x4 b, f32x4 c) {
    return __builtin_amdgcn_mfma_f32_16x16x32_bf16(
        __builtin_bit_cast(bf16x8, a), __builtin_bit_cast(bf16x8, b), c, 0, 0, 0);
}
static __device__ __forceinline__ f32x16 mfma32(u32x4 a, u32x4 b, f32x16 c) {
    return __builtin_amdgcn_mfma_f32_32x32x16_bf16(
        __builtin_bit_cast(bf16x8, a), __builtin_bit_cast(bf16x8, b), c, 0, 0, 0);
}

static __device__ __forceinline__ u32x4 cvt8(const float* __restrict__ p) {
    float4 a = *(const float4*)p;
    float4 b = *(const float4*)(p + 4);
    u32x4 r;
    r.x = (unsigned)f2bf(a.x) | ((unsigned)f2bf(a.y) << 16);
    r.y = (unsigned)f2bf(a.z) | ((unsigned)f2bf(a.w) << 16);
    r.z = (unsigned)f2bf(b.x) | ((unsigned)f2bf(b.y) << 16);
    r.w = (unsigned)f2bf(b.z) | ((unsigned)f2bf(b.w) << 16);
    return r;
}

// adj = (max(1 - |2*dot - si - sj|/64, 0))^1.4
static __device__ __forceinline__ float adj_fn(float dot, float sij) {
    float x = fabsf(fmaf(2.0f, dot, -sij));
    float base = fmaxf(fmaf(-0.015625f, x, 1.0f), 0.0f);
    return exp2f(1.4f * __log2f(base));   // pow(0,1.4)=0 via -inf
}

// ---------------- prep: bbn -> bf16 (row-major), row sums s ----------------
__global__ void prep_kernel(const float* __restrict__ bbn,
                            unsigned short* __restrict__ tbf,
                            float* __restrict__ s) {
    int gid = blockIdx.x * blockDim.x + threadIdx.x;  // 16 threads/row
    int row = gid >> 4;
    int part = gid & 15;
    float4 v = *(const float4*)(bbn + row * BD + part * 4);
    ushort4 o;
    o.x = f2bf(v.x); o.y = f2bf(v.y); o.z = f2bf(v.z); o.w = f2bf(v.w);
    *(ushort4*)(tbf + row * BD + part * 4) = o;
    float ps = v.x + v.y + v.z + v.w;
    ps += __shfl_xor(ps, 1); ps += __shfl_xor(ps, 2);
    ps += __shfl_xor(ps, 4); ps += __shfl_xor(ps, 8);
    if (part == 0) s[row] = ps;
}

// ---------------- prep_cw: cbn -> A-frag bf16, W -> B-frag bf16 (16x16x32 frags) ----------------
__global__ __launch_bounds__(256) void prep_cw_kernel(const float* __restrict__ cbn,
                                                      const float* __restrict__ W,
                                                      unsigned short* __restrict__ cbnF,
                                                      unsigned short* __restrict__ WF) {
    const int lane = threadIdx.x & 63;
    const int wave = threadIdx.x >> 6;
    const int m = lane & 15, q = lane >> 4;
    if (blockIdx.x < 512) {
#pragma unroll
        for (int t = 0; t < 4; ++t) {
            int f = blockIdx.x * 16 + wave * 4 + t;   // 8192 frags
            int it = f >> 4, ct = f & 15;
            u32x4 v = cvt8(cbn + (size_t)(it * 16 + m) * CDIM + ct * 32 + q * 8);
            *(u32x4*)(cbnF + (size_t)f * 512 + lane * 8) = v;
        }
    } else {
#pragma unroll
        for (int t = 0; t < 4; ++t) {
            int f = (blockIdx.x - 512) * 16 + wave * 4 + t;   // 512 frags
            int nt = f >> 4, ct = f & 15;
            u32x4 v = cvt8(W + (size_t)(nt * 16 + m) * CDIM + ct * 32 + q * 8);
            *(u32x4*)(WF + (size_t)f * 512 + lane * 8) = v;
        }
    }
}

// ---------------- scoredeg: adjF = 32x32x16-A-frag bf16 adj, d[i] = row sums ----------------
// grid (128 i-tiles of 64, 16 j-chunks of 512). Wave-private LDS transpose, no barriers.
__global__ __launch_bounds__(256) void scoredeg_kernel(const unsigned short* __restrict__ tbf,
                                                       const float* __restrict__ s,
                                                       float* __restrict__ d,
                                                       unsigned short* __restrict__ adjF) {
    const int lane = threadIdx.x & 63;
    const int wave = threadIdx.x >> 6;   // 0..3
    const int m = lane & 15, q = lane >> 4;
    const int i0 = blockIdx.x * 64;
    const int jbase = blockIdx.y * 512;

    // per-wave private strip: [64 i-rows][32 j + pad8] = 5 KB/wave (20 KB total)
    __shared__ __align__(16) unsigned short T[4][64][40];

    u32x4 afr[4][2];
    float si[4][4];
#pragma unroll
    for (int mt = 0; mt < 4; ++mt) {
#pragma unroll
        for (int ks = 0; ks < 2; ++ks)
            afr[mt][ks] = *(const u32x4*)(tbf + (i0 + mt * 16 + m) * BD + ks * 32 + q * 8);
#pragma unroll
        for (int r = 0; r < 4; ++r) si[mt][r] = s[i0 + mt * 16 + q * 4 + r];
    }
    float dsum[4][4] = {};

    for (int iter = 0; iter < 4; ++iter) {
        const int jw = jbase + iter * 128 + wave * 32;   // this wave's 32-j strip
        u32x4 b[2][2];
        float sj[2];
#pragma unroll
        for (int jh = 0; jh < 2; ++jh) {
            b[jh][0] = *(const u32x4*)(tbf + (jw + jh * 16 + m) * BD + q * 8);
            b[jh][1] = *(const u32x4*)(tbf + (jw + jh * 16 + m) * BD + 32 + q * 8);
            sj[jh] = s[jw + jh * 16 + m];
        }
        f32x4 c[4][2];
#pragma unroll
        for (int mt = 0; mt < 4; ++mt)
#pragma unroll
            for (int jh = 0; jh < 2; ++jh) {
                f32x4 t = {0.f, 0.f, 0.f, 0.f};
                t = mfma16(afr[mt][0], b[jh][0], t);
                t = mfma16(afr[mt][1], b[jh][1], t);
                c[mt][jh] = t;
            }
        // transform + write full 64x32 strip (C-layout in, b16 scatter)
#pragma unroll
        for (int mt = 0; mt < 4; ++mt)
#pragma unroll
            for (int jh = 0; jh < 2; ++jh)
#pragma unroll
                for (int r = 0; r < 4; ++r) {
                    float a = adj_fn(c[mt][jh][r], si[mt][r] + sj[jh]);
                    dsum[mt][r] += a;
                    T[wave][mt * 16 + q * 4 + r][jh * 16 + m] = f2bf(a);
                }
        // read out 4 A32-frags (32 rows x 16 k each) and store frag-major
#pragma unroll
        for (int ih = 0; ih < 2; ++ih)
#pragma unroll
            for (int jh = 0; jh < 2; ++jh) {
                u32x4 v = *(const u32x4*)&T[wave][ih * 32 + (lane & 31)][jh * 16 + (lane >> 5) * 8];
                *(u32x4*)(adjF + (((size_t)(i0 >> 5) + ih) * 512 + (jw >> 4) + jh) * 512 + lane * 8) = v;
            }
    }

#pragma unroll
    for (int mt = 0; mt < 4; ++mt)
#pragma unroll
        for (int r = 0; r < 4; ++r) {
            float v = dsum[mt][r];
            v += __shfl_xor(v, 1); v += __shfl_xor(v, 2);
            v += __shfl_xor(v, 4); v += __shfl_xor(v, 8);
            if (m == 0) atomicAdd(&d[i0 + mt * 16 + q * 4 + r], v);
        }
}

// ---------------- fc: fcF = 32x32x16-B-frag bf16(rsqrt(d[i])*(cbnF @ WF + b)); emits dinv ----------------
__global__ __launch_bounds__(256) void fc_kernel(const unsigned short* __restrict__ cbnF,
                                                 const unsigned short* __restrict__ WF,
                                                 const float* __restrict__ bias,
                                                 const float* __restrict__ dvec,
                                                 float* __restrict__ dinv,
                                                 unsigned short* __restrict__ fcF) {
    const int lane = threadIdx.x & 63;
    const int wave = threadIdx.x >> 6;
    const int m = lane & 15, q = lane >> 4;
    const int i0 = blockIdx.x * 64;
    const int ntg = blockIdx.y * 4 + wave;   // 0..31 (16-col group)

    const u32x4* Ag = (const u32x4*)cbnF;
    const u32x4* Bg = (const u32x4*)WF;

    f32x4 acc[4] = {};
#pragma unroll
    for (int ct = 0; ct < 16; ++ct) {
        u32x4 bfr = Bg[((size_t)ntg * 16 + ct) * 64 + lane];
#pragma unroll
        for (int mt = 0; mt < 4; ++mt) {
            u32x4 afr = Ag[(((size_t)(i0 >> 4) + mt) * 16 + ct) * 64 + lane];
            acc[mt] = mfma16(afr, bfr, acc[mt]);
        }
    }
    float bv = bias[ntg * 16 + m];
    const int n = ntg * 16 + m;   // fc output col (conv2 n)
#pragma unroll
    for (int mt = 0; mt < 4; ++mt) {
        int i = i0 + mt * 16 + q * 4;   // conv2 k-index (fc row)
        ushort4 o;
        o.x = f2bf((acc[mt][0] + bv) * rsqrtf(dvec[i + 0] + 1e-8f));
        o.y = f2bf((acc[mt][1] + bv) * rsqrtf(dvec[i + 1] + 1e-8f));
        o.z = f2bf((acc[mt][2] + bv) * rsqrtf(dvec[i + 2] + 1e-8f));
        o.w = f2bf((acc[mt][3] + bv) * rsqrtf(dvec[i + 3] + 1e-8f));
        // B32-frag scatter: frag(nt32=n>>5, kt16=i>>4); lane'=(n&31)+32*(q>>1); e=(q&1)*4+r
        size_t off = (((size_t)(n >> 5)) * 512 + (i >> 4)) * 512
                   + (size_t)((n & 31) + 32 * (q >> 1)) * 8 + (q & 1) * 4;
        *(ushort4*)(fcF + off) = o;
    }
    if (blockIdx.y == 0 && threadIdx.x < 64)
        dinv[i0 + threadIdx.x] = rsqrtf(dvec[i0 + threadIdx.x] + 1e-8f);
}

// ---------------- conv2: out = sigmoid(dvi * (adj @ fc2)) — 32x32x16 frag GEMM ----------------
// M=8192 N=512 K=8192. Block 128x128, 8 waves: wave = 32-row band x 64-col half.
// Per k-step: ONE A-frag LDS read feeds 2 MFMAs (2x less LDS than 16x16) -> MFMA-bound.
// K-chunk 128 (8 kt16) dbuf LDS 64 KB, 1 barrier/chunk. B: depth-4 register ring from
// global (32 KB unique/chunk, 4x band-dup served by L1).
__global__ __launch_bounds__(512) void conv2_kernel(const unsigned short* __restrict__ adjF,
                                                    const unsigned short* __restrict__ fcF,
                                                    const float* __restrict__ dinv,
                                                    float* __restrict__ out) {
    const int bid = blockIdx.x;
    const int xcd = bid & 7;
    const int g = bid >> 3;               // 0..31
    const int iblk = (g >> 2) * 8 + xcd;  // A-slice cluster co-resident per XCD
    const int cblk = g & 3;
    const int i0 = iblk * 128;

    const int lane = threadIdx.x & 63;
    const int wave = threadIdx.x >> 6;    // 0..7
    const int band = wave >> 1;           // 32-row band 0..3
    const int half = wave & 1;            // col half
    const int nt0 = cblk * 4 + half * 2;  // first of this wave's two 32-col tiles

    __shared__ __align__(16) unsigned short Abuf[2][4][8][512];  // 64 KB [buf][band][kt][frag]

    const u32x4* Ag = (const u32x4*)adjF;
    const u32x4* Bg = (const u32x4*)fcF;
    const size_t abase = ((size_t)iblk * 4 + band) * 512;  // A frag row-base (it32*512)

    f32x16 acc[2] = {};
    u32x4 st[4], bq[4][2];

    // prologue: stage chunk 0 (wave stages band=wave>>1, kt half=wave&1), preload B kt 0..3
#pragma unroll
    for (int t = 0; t < 4; ++t)
        st[t] = Ag[(abase + half * 4 + t) * 64 + lane];
#pragma unroll
    for (int sp = 0; sp < 4; ++sp) {
        bq[sp][0] = Bg[((size_t)(nt0 + 0) * 512 + sp) * 64 + lane];
        bq[sp][1] = Bg[((size_t)(nt0 + 1) * 512 + sp) * 64 + lane];
    }
#pragma unroll
    for (int t = 0; t < 4; ++t)
        *(u32x4*)&Abuf[0][band][half * 4 + t][lane * 8] = st[t];
    __syncthreads();

    for (int c = 0; c < 64; ++c) {
        const int cur = c & 1, nxt = cur ^ 1;
        const int kb = c * 8;
        const int cn = (c < 63) ? c + 1 : c;
        // A: prefetch next chunk into regs (whole MFMA phase covers latency)
#pragma unroll
        for (int t = 0; t < 4; ++t)
            st[t] = Ag[(abase + cn * 8 + half * 4 + t) * 64 + lane];
        // consume 8 k-steps; B ring rolls 4 ahead
#pragma unroll
        for (int sstep = 0; sstep < 8; ++sstep) {
            const int idx = sstep & 3;
            u32x4 b0 = bq[idx][0], b1 = bq[idx][1];
            int ktn = kb + sstep + 4; if (ktn > 511) ktn = 511;
            bq[idx][0] = Bg[((size_t)(nt0 + 0) * 512 + ktn) * 64 + lane];
            bq[idx][1] = Bg[((size_t)(nt0 + 1) * 512 + ktn) * 64 + lane];
            u32x4 pa = *(const u32x4*)&Abuf[cur][band][sstep][lane * 8];
            acc[0] = mfma32(pa, b0, acc[0]);
            acc[1] = mfma32(pa, b1, acc[1]);
        }
        // publish chunk c+1 (buf[nxt] last read in c-1; one barrier suffices)
#pragma unroll
        for (int t = 0; t < 4; ++t)
            *(u32x4*)&Abuf[nxt][band][half * 4 + t][lane * 8] = st[t];
        __syncthreads();
    }

    // epilogue: 32x32 C layout: row=(reg&3)+8*(reg>>2)+4*(lane>>5), col=lane&31
    const int colb = cblk * 128 + half * 64 + (lane & 31);
#pragma unroll
    for (int r = 0; r < 16; ++r) {
        int row = i0 + band * 32 + (r & 3) + 8 * (r >> 2) + 4 * (lane >> 5);
        float dv = dinv[row];
        float x0 = acc[0][r] * dv;
        float x1 = acc[1][r] * dv;
        out[(size_t)row * CDIM + colb]      = 1.0f / (1.0f + __expf(-x0));
        out[(size_t)row * CDIM + colb + 32] = 1.0f / (1.0f + __expf(-x1));
    }
}

extern "C" void kernel_launch(void* const* d_in, const int* in_sizes, int n_in,
                              void* d_out, int out_size, void* d_ws, size_t ws_size,
                              hipStream_t stream) {
    const float* bbn = (const float*)d_in[0];
    const float* cbn = (const float*)d_in[1];
    const float* W   = (const float*)d_in[2];
    const float* b   = (const float*)d_in[3];
    float* out = (float*)d_out;  // reference output is float32

    char* ws = (char*)d_ws;
    unsigned short* tbf  = (unsigned short*)(ws);                 // 1 MB
    float* s             = (float*)(ws + (1u << 20));             // 32 KB
    float* d             = (float*)(ws + (1u << 20) + 32768);     // 32 KB
    float* dinv          = (float*)(ws + (1u << 20) + 65536);     // 32 KB
    unsigned short* fcF  = (unsigned short*)(ws + (2u << 20));    // 8 MB
    unsigned short* cbnF = (unsigned short*)(ws + (10u << 20));   // 8 MB
    unsigned short* WF   = (unsigned short*)(ws + (18u << 20));   // 0.5 MB
    unsigned short* adjF = (unsigned short*)(ws + (19u << 20));   // 128 MiB

    prep_kernel<<<NN * 16 / 256, 256, 0, stream>>>(bbn, tbf, s);
    prep_cw_kernel<<<544, 256, 0, stream>>>(cbn, W, cbnF, WF);
    hipMemsetAsync(d, 0, NN * sizeof(float), stream);
    scoredeg_kernel<<<dim3(NN / 64, 16), 256, 0, stream>>>(tbf, s, d, adjF);
    fc_kernel<<<dim3(NN / 64, 8), 256, 0, stream>>>(cbnF, WF, b, d, dinv, fcF);
    conv2_kernel<<<256, 512, 0, stream>>>(adjF, fcF, dinv, out);
}

// Round 10
// 228.120 us; speedup vs baseline: 1.0675x; 1.0675x over previous
//
#include <hip/hip_runtime.h>
#include <hip/hip_bf16.h>

// N=8192 rows, BD=64 code dim, CD=512 channel dim
#define NN 8192
#define BD 64
#define CDIM 512

typedef __attribute__((ext_vector_type(4))) float f32x4;
typedef __attribute__((ext_vector_type(16))) float f32x16;
typedef __attribute__((ext_vector_type(4))) unsigned int u32x4;
typedef __attribute__((ext_vector_type(8))) __bf16 bf16x8;

// 32x32x16 fragment-major layouts (elems = unsigned short), frag = 512 ushorts = 1 KB:
//  adjF frag(it32,kt16): it32=i/32 [0,256), kt16=k/16 [0,512): off=(it32*512+kt16)*512+lane*8
//    lane l holds adj[it32*32 + (l&31)][kt16*16 + (l>>5)*8 + e]      (A-operand)
//  fcF  frag(nt32,kt16): nt32=n/32 [0,16),  kt16=k/16 [0,512): off=(nt32*512+kt16)*512+lane*8
//    lane l holds fc2[kt16*16 + (l>>5)*8 + e][nt32*32 + (l&31)]     (B-operand)
//  cbnF/WF stay 16x16x32 frags for the small fc GEMM.

static __device__ __forceinline__ unsigned short f2bf(float x) {
    unsigned int u = __float_as_uint(x);
    u += 0x7fffu + ((u >> 16) & 1u);   // RTNE
    return (unsigned short)(u >> 16);
}

static __device__ __forceinline__ f32x4 mfma16(u32x4 a, u32x4 b, f32x4 c) {
    return __builtin_amdgcn_mfma_f32_16x16x32_bf16(
        __builtin_bit_cast(bf16x8, a), __builtin_bit_cast(bf16x8, b), c, 0, 0, 0);
}
static __device__ __forceinline__ f32x16 mfma32(u32x4 a, u32x4 b, f32x16 c) {
    return __builtin_amdgcn_mfma_f32_32x32x16_bf16(
        __builtin_bit_cast(bf16x8, a), __builtin_bit_cast(bf16x8, b), c, 0, 0, 0);
}

static __device__ __forceinline__ u32x4 cvt8(const float* __restrict__ p) {
    float4 a = *(const float4*)p;
    float4 b = *(const float4*)(p + 4);
    u32x4 r;
    r.x = (unsigned)f2bf(a.x) | ((unsigned)f2bf(a.y) << 16);
    r.y = (unsigned)f2bf(a.z) | ((unsigned)f2bf(a.w) << 16);
    r.z = (unsigned)f2bf(b.x) | ((unsigned)f2bf(b.y) << 16);
    r.w = (unsigned)f2bf(b.z) | ((unsigned)f2bf(b.w) << 16);
    return r;
}

// adj = (max(1 - |2*dot - si - sj|/64, 0))^1.4
static __device__ __forceinline__ float adj_fn(float dot, float sij) {
    float x = fabsf(fmaf(2.0f, dot, -sij));
    float base = fmaxf(fmaf(-0.015625f, x, 1.0f), 0.0f);
    return exp2f(1.4f * __log2f(base));   // pow(0,1.4)=0 via -inf
}

// ---------------- prep (merged): bbn->tbf+s, d=0, cbn->cbnF, W->WF ----------------
__global__ __launch_bounds__(256) void prep_all_kernel(const float* __restrict__ bbn,
                                                       const float* __restrict__ cbn,
                                                       const float* __restrict__ W,
                                                       unsigned short* __restrict__ tbf,
                                                       float* __restrict__ s,
                                                       float* __restrict__ dzero,
                                                       unsigned short* __restrict__ cbnF,
                                                       unsigned short* __restrict__ WF) {
    const int bid = blockIdx.x;
    const int lane = threadIdx.x & 63;
    const int wave = threadIdx.x >> 6;
    const int m = lane & 15, q = lane >> 4;
    if (bid < 512) {
        int gid = bid * 256 + threadIdx.x;  // 16 threads/row
        int row = gid >> 4;
        int part = gid & 15;
        float4 v = *(const float4*)(bbn + row * BD + part * 4);
        ushort4 o;
        o.x = f2bf(v.x); o.y = f2bf(v.y); o.z = f2bf(v.z); o.w = f2bf(v.w);
        *(ushort4*)(tbf + row * BD + part * 4) = o;
        float ps = v.x + v.y + v.z + v.w;
        ps += __shfl_xor(ps, 1); ps += __shfl_xor(ps, 2);
        ps += __shfl_xor(ps, 4); ps += __shfl_xor(ps, 8);
        if (part == 0) s[row] = ps;
        if (bid < 32) dzero[bid * 256 + threadIdx.x] = 0.0f;
    } else if (bid < 1024) {
#pragma unroll
        for (int t = 0; t < 4; ++t) {
            int f = (bid - 512) * 16 + wave * 4 + t;   // 8192 frags
            int it = f >> 4, ct = f & 15;
            u32x4 v = cvt8(cbn + (size_t)(it * 16 + m) * CDIM + ct * 32 + q * 8);
            *(u32x4*)(cbnF + (size_t)f * 512 + lane * 8) = v;
        }
    } else {
#pragma unroll
        for (int t = 0; t < 4; ++t) {
            int f = (bid - 1024) * 16 + wave * 4 + t;  // 512 frags
            int nt = f >> 4, ct = f & 15;
            u32x4 v = cvt8(W + (size_t)(nt * 16 + m) * CDIM + ct * 32 + q * 8);
            *(u32x4*)(WF + (size_t)f * 512 + lane * 8) = v;
        }
    }
}

// ---------------- scoredeg: adjF = 32x32x16-A-frag bf16 adj, d[i] = row sums ----------------
// grid (128 i-tiles of 64, 16 j-chunks of 512). Wave-private LDS transpose, no barriers.
__global__ __launch_bounds__(256) void scoredeg_kernel(const unsigned short* __restrict__ tbf,
                                                       const float* __restrict__ s,
                                                       float* __restrict__ d,
                                                       unsigned short* __restrict__ adjF) {
    const int lane = threadIdx.x & 63;
    const int wave = threadIdx.x >> 6;   // 0..3
    const int m = lane & 15, q = lane >> 4;
    const int i0 = blockIdx.x * 64;
    const int jbase = blockIdx.y * 512;

    // per-wave private strip: [64 i-rows][32 j + pad8] = 5 KB/wave (20 KB total)
    __shared__ __align__(16) unsigned short T[4][64][40];

    u32x4 afr[4][2];
    float si[4][4];
#pragma unroll
    for (int mt = 0; mt < 4; ++mt) {
#pragma unroll
        for (int ks = 0; ks < 2; ++ks)
            afr[mt][ks] = *(const u32x4*)(tbf + (i0 + mt * 16 + m) * BD + ks * 32 + q * 8);
#pragma unroll
        for (int r = 0; r < 4; ++r) si[mt][r] = s[i0 + mt * 16 + q * 4 + r];
    }
    float dsum[4][4] = {};

    for (int iter = 0; iter < 4; ++iter) {
        const int jw = jbase + iter * 128 + wave * 32;   // this wave's 32-j strip
        u32x4 b[2][2];
        float sj[2];
#pragma unroll
        for (int jh = 0; jh < 2; ++jh) {
            b[jh][0] = *(const u32x4*)(tbf + (jw + jh * 16 + m) * BD + q * 8);
            b[jh][1] = *(const u32x4*)(tbf + (jw + jh * 16 + m) * BD + 32 + q * 8);
            sj[jh] = s[jw + jh * 16 + m];
        }
        f32x4 c[4][2];
#pragma unroll
        for (int mt = 0; mt < 4; ++mt)
#pragma unroll
            for (int jh = 0; jh < 2; ++jh) {
                f32x4 t = {0.f, 0.f, 0.f, 0.f};
                t = mfma16(afr[mt][0], b[jh][0], t);
                t = mfma16(afr[mt][1], b[jh][1], t);
                c[mt][jh] = t;
            }
        // transform + write full 64x32 strip (C-layout in, b16 scatter)
#pragma unroll
        for (int mt = 0; mt < 4; ++mt)
#pragma unroll
            for (int jh = 0; jh < 2; ++jh)
#pragma unroll
                for (int r = 0; r < 4; ++r) {
                    float a = adj_fn(c[mt][jh][r], si[mt][r] + sj[jh]);
                    dsum[mt][r] += a;
                    T[wave][mt * 16 + q * 4 + r][jh * 16 + m] = f2bf(a);
                }
        // read out 4 A32-frags (32 rows x 16 k each) and store frag-major
#pragma unroll
        for (int ih = 0; ih < 2; ++ih)
#pragma unroll
            for (int jh = 0; jh < 2; ++jh) {
                u32x4 v = *(const u32x4*)&T[wave][ih * 32 + (lane & 31)][jh * 16 + (lane >> 5) * 8];
                *(u32x4*)(adjF + (((size_t)(i0 >> 5) + ih) * 512 + (jw >> 4) + jh) * 512 + lane * 8) = v;
            }
    }

#pragma unroll
    for (int mt = 0; mt < 4; ++mt)
#pragma unroll
        for (int r = 0; r < 4; ++r) {
            float v = dsum[mt][r];
            v += __shfl_xor(v, 1); v += __shfl_xor(v, 2);
            v += __shfl_xor(v, 4); v += __shfl_xor(v, 8);
            if (m == 0) atomicAdd(&d[i0 + mt * 16 + q * 4 + r], v);
        }
}

// ---------------- fc: fcF = 32x32x16-B-frag bf16(rsqrt(d[i])*(cbnF @ WF + b)); emits dinv ----------------
__global__ __launch_bounds__(256) void fc_kernel(const unsigned short* __restrict__ cbnF,
                                                 const unsigned short* __restrict__ WF,
                                                 const float* __restrict__ bias,
                                                 const float* __restrict__ dvec,
                                                 float* __restrict__ dinv,
                                                 unsigned short* __restrict__ fcF) {
    const int lane = threadIdx.x & 63;
    const int wave = threadIdx.x >> 6;
    const int m = lane & 15, q = lane >> 4;
    const int i0 = blockIdx.x * 64;
    const int ntg = blockIdx.y * 4 + wave;   // 0..31 (16-col group)

    const u32x4* Ag = (const u32x4*)cbnF;
    const u32x4* Bg = (const u32x4*)WF;

    f32x4 acc[4] = {};
#pragma unroll
    for (int ct = 0; ct < 16; ++ct) {
        u32x4 bfr = Bg[((size_t)ntg * 16 + ct) * 64 + lane];
#pragma unroll
        for (int mt = 0; mt < 4; ++mt) {
            u32x4 afr = Ag[(((size_t)(i0 >> 4) + mt) * 16 + ct) * 64 + lane];
            acc[mt] = mfma16(afr, bfr, acc[mt]);
        }
    }
    float bv = bias[ntg * 16 + m];
    const int n = ntg * 16 + m;   // fc output col (conv2 n)
#pragma unroll
    for (int mt = 0; mt < 4; ++mt) {
        int i = i0 + mt * 16 + q * 4;   // conv2 k-index (fc row)
        ushort4 o;
        o.x = f2bf((acc[mt][0] + bv) * rsqrtf(dvec[i + 0] + 1e-8f));
        o.y = f2bf((acc[mt][1] + bv) * rsqrtf(dvec[i + 1] + 1e-8f));
        o.z = f2bf((acc[mt][2] + bv) * rsqrtf(dvec[i + 2] + 1e-8f));
        o.w = f2bf((acc[mt][3] + bv) * rsqrtf(dvec[i + 3] + 1e-8f));
        // B32-frag scatter: frag(nt32=n>>5, kt16=i>>4); lane'=(n&31)+32*(q>>1); e=(q&1)*4+r
        size_t off = (((size_t)(n >> 5)) * 512 + (i >> 4)) * 512
                   + (size_t)((n & 31) + 32 * (q >> 1)) * 8 + (q & 1) * 4;
        *(ushort4*)(fcF + off) = o;
    }
    if (blockIdx.y == 0 && threadIdx.x < 64)
        dinv[i0 + threadIdx.x] = rsqrtf(dvec[i0 + threadIdx.x] + 1e-8f);
}

// ---------------- conv2: out = sigmoid(dvi * (adj @ fc2)) — 32x32x16 frag GEMM ----------------
// M=8192 N=512 K=8192. Block 128x128, 8 waves = 2 row-bands(64) x 4 col-groups(32).
// Per kt16 per wave: 2 A-frag LDS reads + 1 B-frag global load + 2 mfma32.
// Per-chunk/CU: LDS-A 128 KB (~1540 cyc), L2-B 64 KB (~1170), MFMA 1033 — balanced.
// Swizzle: per XCD only 2 cblks -> B hot set 4 MB = L2-resident. A-slice spans an XCD
// pair; adjF is L3-resident so the second XCD reads L3, not HBM.
__global__ __launch_bounds__(512) void conv2_kernel(const unsigned short* __restrict__ adjF,
                                                    const unsigned short* __restrict__ fcF,
                                                    const float* __restrict__ dinv,
                                                    float* __restrict__ out) {
    const int bid = blockIdx.x;
    const int xcd = bid & 7;
    const int g = bid >> 3;                        // 0..31
    const int iblk = (xcd >> 1) * 16 + (g >> 1);   // 0..63
    const int cblk = 2 * (xcd & 1) + (g & 1);      // 0..3
    const int i0 = iblk * 128;

    const int lane = threadIdx.x & 63;
    const int wave = threadIdx.x >> 6;    // 0..7
    const int band = wave >> 2;           // 0..1: 64-row band
    const int cg = wave & 3;              // 0..3: 32-col group
    const int nt32 = cblk * 4 + cg;       // 0..15

    __shared__ __align__(16) unsigned short Abuf[2][4][8][512];  // [buf][it32][kt16][frag] 64 KB

    const u32x4* Ag = (const u32x4*)adjF;
    const u32x4* Bg = (const u32x4*)fcF;
    // staging: wave stages it32 = wave>>1, kt-half = wave&1 (4 frags = 4 KB)
    const int sit = wave >> 1;
    const int skh = wave & 1;
    const size_t abase = ((size_t)(iblk * 4 + sit)) * 512;

    f32x16 acc[2] = {};
    u32x4 st[4], bq[4];

    // prologue: stage chunk 0, preload B kt 0..3
#pragma unroll
    for (int t = 0; t < 4; ++t)
        st[t] = Ag[(abase + skh * 4 + t) * 64 + lane];
#pragma unroll
    for (int sp = 0; sp < 4; ++sp)
        bq[sp] = Bg[((size_t)nt32 * 512 + sp) * 64 + lane];
#pragma unroll
    for (int t = 0; t < 4; ++t)
        *(u32x4*)&Abuf[0][sit][skh * 4 + t][lane * 8] = st[t];
    __syncthreads();

    for (int c = 0; c < 64; ++c) {
        const int cur = c & 1, nxt = cur ^ 1;
        const int kb = c * 8;
        const int cn = (c < 63) ? c + 1 : c;
        // A: prefetch next chunk into regs (whole MFMA phase covers latency)
#pragma unroll
        for (int t = 0; t < 4; ++t)
            st[t] = Ag[(abase + cn * 8 + skh * 4 + t) * 64 + lane];
        // consume 8 kt16 steps; B ring rolls 4 ahead
#pragma unroll
        for (int ks = 0; ks < 8; ++ks) {
            const int idx = ks & 3;
            u32x4 b = bq[idx];
            int ktn = kb + ks + 4; if (ktn > 511) ktn = 511;
            bq[idx] = Bg[((size_t)nt32 * 512 + ktn) * 64 + lane];
            u32x4 a0 = *(const u32x4*)&Abuf[cur][band * 2 + 0][ks][lane * 8];
            u32x4 a1 = *(const u32x4*)&Abuf[cur][band * 2 + 1][ks][lane * 8];
            acc[0] = mfma32(a0, b, acc[0]);
            acc[1] = mfma32(a1, b, acc[1]);
        }
        // publish chunk c+1 (buf[nxt] last read in c-1; one barrier suffices)
#pragma unroll
        for (int t = 0; t < 4; ++t)
            *(u32x4*)&Abuf[nxt][sit][skh * 4 + t][lane * 8] = st[t];
        __syncthreads();
    }

    // epilogue: 32x32 C layout: row=(r&3)+8*(r>>2)+4*(lane>>5), col=lane&31
    const int colb = cblk * 128 + cg * 32 + (lane & 31);
#pragma unroll
    for (int mt = 0; mt < 2; ++mt)
#pragma unroll
        for (int r = 0; r < 16; ++r) {
            int row = i0 + (band * 2 + mt) * 32 + (r & 3) + 8 * (r >> 2) + 4 * (lane >> 5);
            float dv = dinv[row];
            float xv = acc[mt][r] * dv;
            out[(size_t)row * CDIM + colb] = 1.0f / (1.0f + __expf(-xv));
        }
}

extern "C" void kernel_launch(void* const* d_in, const int* in_sizes, int n_in,
                              void* d_out, int out_size, void* d_ws, size_t ws_size,
                              hipStream_t stream) {
    const float* bbn = (const float*)d_in[0];
    const float* cbn = (const float*)d_in[1];
    const float* W   = (const float*)d_in[2];
    const float* b   = (const float*)d_in[3];
    float* out = (float*)d_out;  // reference output is float32

    char* ws = (char*)d_ws;
    unsigned short* tbf  = (unsigned short*)(ws);                 // 1 MB
    float* s             = (float*)(ws + (1u << 20));             // 32 KB
    float* d             = (float*)(ws + (1u << 20) + 32768);     // 32 KB
    float* dinv          = (float*)(ws + (1u << 20) + 65536);     // 32 KB
    unsigned short* fcF  = (unsigned short*)(ws + (2u << 20));    // 8 MB
    unsigned short* cbnF = (unsigned short*)(ws + (10u << 20));   // 8 MB
    unsigned short* WF   = (unsigned short*)(ws + (18u << 20));   // 0.5 MB
    unsigned short* adjF = (unsigned short*)(ws + (19u << 20));   // 128 MiB

    prep_all_kernel<<<1056, 256, 0, stream>>>(bbn, cbn, W, tbf, s, d, cbnF, WF);
    scoredeg_kernel<<<dim3(NN / 64, 16), 256, 0, stream>>>(tbf, s, d, adjF);
    fc_kernel<<<dim3(NN / 64, 8), 256, 0, stream>>>(cbnF, WF, b, d, dinv, fcF);
    conv2_kernel<<<256, 512, 0, stream>>>(adjF, fcF, dinv, out);
}